// Round 1
// baseline (143.107 us; speedup 1.0000x reference)
//
#include <hip/hip_runtime.h>

#define NN 1024
#define HH 128
#define QR 2
#define RPB 4
#define TPB 512

__device__ __forceinline__ float4 wmax4(float4 v) {
#pragma unroll
  for (int off = 1; off < 64; off <<= 1) {
    v.x = fmaxf(v.x, __shfl_xor(v.x, off));
    v.y = fmaxf(v.y, __shfl_xor(v.y, off));
    v.z = fmaxf(v.z, __shfl_xor(v.z, off));
    v.w = fmaxf(v.w, __shfl_xor(v.w, off));
  }
  return v;
}

__device__ __forceinline__ float4 wsum4(float4 v) {
#pragma unroll
  for (int off = 1; off < 64; off <<= 1) {
    v.x += __shfl_xor(v.x, off);
    v.y += __shfl_xor(v.y, off);
    v.z += __shfl_xor(v.z, off);
    v.w += __shfl_xor(v.w, off);
  }
  return v;
}

// ---------------- prep: W transposes + edge param pack + c0 ----------------
__global__ __launch_bounds__(128)
void prep_kernel(const float* __restrict__ Wq, const float* __restrict__ Wk,
                 const float* __restrict__ Wv, const float* __restrict__ We1,
                 const float* __restrict__ be1, const float* __restrict__ We2,
                 const float* __restrict__ be2, const float* __restrict__ Wc,
                 const float* __restrict__ bc,
                 float* __restrict__ WqT, float* __restrict__ WkT,
                 float* __restrict__ WvT, float* __restrict__ epack,
                 float* __restrict__ c0) {
  const int d = blockIdx.x;
  const int o = threadIdx.x;
  WqT[d * HH + o] = Wq[o * HH + d];
  WkT[d * HH + o] = Wk[o * HH + d];
  WvT[d * HH + o] = Wv[o * HH + d];
  if (d == 0) {
    // u[t] = sum_e Wc[e] * We2[e][t]   (fold Wc @ We2)
    float uu = 0.f;
    for (int e = 0; e < HH; ++e) uu = fmaf(Wc[e], We2[e * HH + o], uu);
    epack[o * 4 + 0] = We1[2 * o];
    epack[o * 4 + 1] = We1[2 * o + 1];
    epack[o * 4 + 2] = be1[o];
    epack[o * 4 + 3] = uu;
    if (o == 0) {
      float s = bc[0];
      for (int e = 0; e < HH; ++e) s = fmaf(Wc[e], be2[e], s);
      c0[0] = s;
    }
  }
}

// ---------------- qkv projections: q,v row-major; k transposed ----------------
__global__ __launch_bounds__(128)
void qkv_kernel(const float* __restrict__ hin,
                const float* __restrict__ WqT, const float* __restrict__ WkT,
                const float* __restrict__ WvT,
                const float* __restrict__ bq, const float* __restrict__ bk,
                const float* __restrict__ bv,
                float* __restrict__ q, float* __restrict__ kT,
                float* __restrict__ v) {
  __shared__ __align__(16) float hT[HH][QR];
  const int tid = threadIdx.x;   // output feature o
  const int i0 = blockIdx.x * QR;
#pragma unroll
  for (int r = 0; r < QR; ++r) hT[tid][r] = hin[(i0 + r) * HH + tid];
  __syncthreads();
  float qa0 = 0.f, qa1 = 0.f, ka0 = 0.f, ka1 = 0.f, va0 = 0.f, va1 = 0.f;
#pragma unroll 4
  for (int d = 0; d < HH; ++d) {
    float wq = WqT[d * HH + tid];
    float wk = WkT[d * HH + tid];
    float wv = WvT[d * HH + tid];
    float2 hh = *(const float2*)&hT[d][0];
    qa0 = fmaf(hh.x, wq, qa0); qa1 = fmaf(hh.y, wq, qa1);
    ka0 = fmaf(hh.x, wk, ka0); ka1 = fmaf(hh.y, wk, ka1);
    va0 = fmaf(hh.x, wv, va0); va1 = fmaf(hh.y, wv, va1);
  }
  float bqv = bq[tid], bkv = bk[tid], bvv = bv[tid];
  q[(i0 + 0) * HH + tid] = qa0 + bqv;
  q[(i0 + 1) * HH + tid] = qa1 + bqv;
  v[(i0 + 0) * HH + tid] = va0 + bvv;
  v[(i0 + 1) * HH + tid] = va1 + bvv;
  float2 kk = make_float2(ka0 + bkv, ka1 + bkv);
  *(float2*)&kT[tid * NN + i0] = kk;   // kT[d][j]
}

// ---------------- fused attention + edge-weighted coordinate update ----------------
__global__ __launch_bounds__(TPB)
void fused_kernel(const float* __restrict__ q, const float* __restrict__ kT,
                  const float* __restrict__ v, const float* __restrict__ hin,
                  const float* __restrict__ x,
                  const float* __restrict__ epack, const float* __restrict__ c0p,
                  float* __restrict__ pws,
                  float* __restrict__ out_h, float* __restrict__ out_x) {
  __shared__ __align__(16) float sredh[8][RPB][HH];   // 16KB PV partials
  __shared__ __align__(16) float4 sredm[8];
  __shared__ __align__(16) float4 sreds[8];
  __shared__ __align__(16) float4 sredx[8];
  __shared__ __align__(16) float4 sredy[8];
  __shared__ __align__(16) float4 sinv;

  const int tid = threadIdx.x;
  const int lane = tid & 63;
  const int wid = tid >> 6;
  const int i0 = blockIdx.x * RPB;
  float* __restrict__ pblk = pws + (size_t)blockIdx.x * (NN * 4);

  // ---- scores: thread owns j0=2*tid, j1=2*tid+1; rows r=0..3 (q via SGPR broadcast)
  float a00 = 0.f, a01 = 0.f, a02 = 0.f, a03 = 0.f;
  float a10 = 0.f, a11 = 0.f, a12 = 0.f, a13 = 0.f;
  const float2* kT2 = (const float2*)kT;
#pragma unroll 8
  for (int d = 0; d < HH; ++d) {
    float2 kk = kT2[d * (NN / 2) + tid];        // coalesced
    float q0 = q[(i0 + 0) * HH + d];            // wave-uniform -> s_load
    float q1 = q[(i0 + 1) * HH + d];
    float q2 = q[(i0 + 2) * HH + d];
    float q3 = q[(i0 + 3) * HH + d];
    a00 = fmaf(q0, kk.x, a00); a10 = fmaf(q0, kk.y, a10);
    a01 = fmaf(q1, kk.x, a01); a11 = fmaf(q1, kk.y, a11);
    a02 = fmaf(q2, kk.x, a02); a12 = fmaf(q2, kk.y, a12);
    a03 = fmaf(q3, kk.x, a03); a13 = fmaf(q3, kk.y, a13);
  }
  const float scale = 0.08838834764831845f;  // 1/sqrt(128)
  float s00 = a00 * scale, s01 = a01 * scale, s02 = a02 * scale, s03 = a03 * scale;
  float s10 = a10 * scale, s11 = a11 * scale, s12 = a12 * scale, s13 = a13 * scale;

  // ---- row max
  float4 mv = make_float4(fmaxf(s00, s10), fmaxf(s01, s11),
                          fmaxf(s02, s12), fmaxf(s03, s13));
  mv = wmax4(mv);
  if (lane == 0) sredm[wid] = mv;
  __syncthreads();
  float4 mm = sredm[0];
#pragma unroll
  for (int w2 = 1; w2 < 8; ++w2) {
    float4 t4 = sredm[w2];
    mm.x = fmaxf(mm.x, t4.x); mm.y = fmaxf(mm.y, t4.y);
    mm.z = fmaxf(mm.z, t4.z); mm.w = fmaxf(mm.w, t4.w);
  }

  // ---- exp (unnormalized p), store to per-block scratch, row sums
  float e00 = __expf(s00 - mm.x), e01 = __expf(s01 - mm.y);
  float e02 = __expf(s02 - mm.z), e03 = __expf(s03 - mm.w);
  float e10 = __expf(s10 - mm.x), e11 = __expf(s11 - mm.y);
  float e12 = __expf(s12 - mm.z), e13 = __expf(s13 - mm.w);
  *(float4*)&pblk[(2 * tid) * 4]     = make_float4(e00, e01, e02, e03);
  *(float4*)&pblk[(2 * tid + 1) * 4] = make_float4(e10, e11, e12, e13);
  float4 sv = make_float4(e00 + e10, e01 + e11, e02 + e12, e03 + e13);
  sv = wsum4(sv);
  if (lane == 0) sreds[wid] = sv;
  __syncthreads();
  float4 ss = sreds[0];
#pragma unroll
  for (int w2 = 1; w2 < 8; ++w2) {
    float4 t4 = sreds[w2];
    ss.x += t4.x; ss.y += t4.y; ss.z += t4.z; ss.w += t4.w;
  }
  if (tid == 0)
    sinv = make_float4(1.f / ss.x, 1.f / ss.y, 1.f / ss.z, 1.f / ss.w);

  // ---- agg_h = p @ v   (8 j-splits x 64 lanes, 2 o per lane, coalesced v)
  const int o2 = (tid & 63) * 2;
  const int sp = tid >> 6;   // 0..7
  float h00 = 0.f, h01 = 0.f, h02 = 0.f, h03 = 0.f;
  float h10 = 0.f, h11 = 0.f, h12 = 0.f, h13 = 0.f;
#pragma unroll 4
  for (int jj = 0; jj < NN / 8; ++jj) {
    int j = sp * (NN / 8) + jj;
    float2 vv = *(const float2*)&v[j * HH + o2];
    float4 pp = *(const float4*)&pblk[j * 4];   // wave-uniform broadcast
    h00 = fmaf(pp.x, vv.x, h00); h10 = fmaf(pp.x, vv.y, h10);
    h01 = fmaf(pp.y, vv.x, h01); h11 = fmaf(pp.y, vv.y, h11);
    h02 = fmaf(pp.z, vv.x, h02); h12 = fmaf(pp.z, vv.y, h12);
    h03 = fmaf(pp.w, vv.x, h03); h13 = fmaf(pp.w, vv.y, h13);
  }
  *(float2*)&sredh[sp][0][o2] = make_float2(h00, h10);
  *(float2*)&sredh[sp][1][o2] = make_float2(h01, h11);
  *(float2*)&sredh[sp][2][o2] = make_float2(h02, h12);
  *(float2*)&sredh[sp][3][o2] = make_float2(h03, h13);
  __syncthreads();
  {
    const int r = tid >> 7;     // 0..3
    const int o = tid & 127;
    float hv = 0.f;
#pragma unroll
    for (int s2 = 0; s2 < 8; ++s2) hv += sredh[s2][r][o];
    float invq = ((const float*)&sinv)[r];
    const int row = i0 + r;
    out_h[row * HH + o] = hin[row * HH + o] + hv * invq;
  }

  // ---- edge-weighted coordinate update
  const int j0 = 2 * tid;
  float4 xx = *(const float4*)&x[j0 * 2];   // {xj0.x, xj0.y, xj1.x, xj1.y}
  float xi0x = x[(i0 + 0) * 2 + 0], xi0y = x[(i0 + 0) * 2 + 1];
  float xi1x = x[(i0 + 1) * 2 + 0], xi1y = x[(i0 + 1) * 2 + 1];
  float xi2x = x[(i0 + 2) * 2 + 0], xi2y = x[(i0 + 2) * 2 + 1];
  float xi3x = x[(i0 + 3) * 2 + 0], xi3y = x[(i0 + 3) * 2 + 1];
  float dxa0 = xi0x - xx.x, dya0 = xi0y - xx.y;
  float dxa1 = xi1x - xx.x, dya1 = xi1y - xx.y;
  float dxa2 = xi2x - xx.x, dya2 = xi2y - xx.y;
  float dxa3 = xi3x - xx.x, dya3 = xi3y - xx.y;
  float dxb0 = xi0x - xx.z, dyb0 = xi0y - xx.w;
  float dxb1 = xi1x - xx.z, dyb1 = xi1y - xx.w;
  float dxb2 = xi2x - xx.z, dyb2 = xi2y - xx.w;
  float dxb3 = xi3x - xx.z, dyb3 = xi3y - xx.w;

  float wa0 = 0.f, wa1 = 0.f, wa2 = 0.f, wa3 = 0.f;
  float wb0 = 0.f, wb1 = 0.f, wb2 = 0.f, wb3 = 0.f;
  const float4* ep4 = (const float4*)epack;
#pragma unroll 4
  for (int t = 0; t < HH; ++t) {
    float4 e = ep4[t];   // wave-uniform {We1_0, We1_1, be1, u}
    float aa;
    aa = fmaxf(fmaf(e.x, dxa0, fmaf(e.y, dya0, e.z)), 0.f); wa0 = fmaf(e.w, aa, wa0);
    aa = fmaxf(fmaf(e.x, dxa1, fmaf(e.y, dya1, e.z)), 0.f); wa1 = fmaf(e.w, aa, wa1);
    aa = fmaxf(fmaf(e.x, dxa2, fmaf(e.y, dya2, e.z)), 0.f); wa2 = fmaf(e.w, aa, wa2);
    aa = fmaxf(fmaf(e.x, dxa3, fmaf(e.y, dya3, e.z)), 0.f); wa3 = fmaf(e.w, aa, wa3);
    aa = fmaxf(fmaf(e.x, dxb0, fmaf(e.y, dyb0, e.z)), 0.f); wb0 = fmaf(e.w, aa, wb0);
    aa = fmaxf(fmaf(e.x, dxb1, fmaf(e.y, dyb1, e.z)), 0.f); wb1 = fmaf(e.w, aa, wb1);
    aa = fmaxf(fmaf(e.x, dxb2, fmaf(e.y, dyb2, e.z)), 0.f); wb2 = fmaf(e.w, aa, wb2);
    aa = fmaxf(fmaf(e.x, dxb3, fmaf(e.y, dyb3, e.z)), 0.f); wb3 = fmaf(e.w, aa, wb3);
  }
  const float c0 = c0p[0];
  float cwa0 = e00 * (wa0 + c0), cwa1 = e01 * (wa1 + c0);
  float cwa2 = e02 * (wa2 + c0), cwa3 = e03 * (wa3 + c0);
  float cwb0 = e10 * (wb0 + c0), cwb1 = e11 * (wb1 + c0);
  float cwb2 = e12 * (wb2 + c0), cwb3 = e13 * (wb3 + c0);
  float4 rx = make_float4(fmaf(cwa0, dxa0, cwb0 * dxb0),
                          fmaf(cwa1, dxa1, cwb1 * dxb1),
                          fmaf(cwa2, dxa2, cwb2 * dxb2),
                          fmaf(cwa3, dxa3, cwb3 * dxb3));
  float4 ry = make_float4(fmaf(cwa0, dya0, cwb0 * dyb0),
                          fmaf(cwa1, dya1, cwb1 * dyb1),
                          fmaf(cwa2, dya2, cwb2 * dyb2),
                          fmaf(cwa3, dya3, cwb3 * dyb3));
  rx = wsum4(rx);
  ry = wsum4(ry);
  if (lane == 0) { sredx[wid] = rx; sredy[wid] = ry; }
  __syncthreads();
  if (tid < 4) {
    float sx = 0.f, sy = 0.f;
#pragma unroll
    for (int w2 = 0; w2 < 8; ++w2) {
      sx += ((const float*)sredx)[w2 * 4 + tid];
      sy += ((const float*)sredy)[w2 * 4 + tid];
    }
    float invr = ((const float*)&sinv)[tid];
    const int row = i0 + tid;
    out_x[row * 2 + 0] = x[row * 2 + 0] + sx * invr;
    out_x[row * 2 + 1] = x[row * 2 + 1] + sy * invr;
  }
}

extern "C" void kernel_launch(void* const* d_in, const int* in_sizes, int n_in,
                              void* d_out, int out_size, void* d_ws, size_t ws_size,
                              hipStream_t stream) {
  (void)in_sizes; (void)n_in; (void)out_size; (void)ws_size;
  const float* h   = (const float*)d_in[0];
  const float* x   = (const float*)d_in[1];
  // d_in[2] = batch (all zeros, unused)
  const float* Wq  = (const float*)d_in[3];
  const float* bq  = (const float*)d_in[4];
  const float* Wk  = (const float*)d_in[5];
  const float* bk  = (const float*)d_in[6];
  const float* Wv  = (const float*)d_in[7];
  const float* bv  = (const float*)d_in[8];
  const float* We1 = (const float*)d_in[9];
  const float* be1 = (const float*)d_in[10];
  const float* We2 = (const float*)d_in[11];
  const float* be2 = (const float*)d_in[12];
  const float* Wc  = (const float*)d_in[13];
  const float* bc  = (const float*)d_in[14];

  float* ws  = (float*)d_ws;
  float* q_  = ws;                  // N*H
  float* kT  = q_ + NN * HH;        // N*H  (transposed: [d][j])
  float* v_  = kT + NN * HH;        // N*H
  float* WqT = v_ + NN * HH;        // H*H
  float* WkT = WqT + HH * HH;
  float* WvT = WkT + HH * HH;
  float* ep  = WvT + HH * HH;       // 4*H packed edge params
  float* c0  = ep + 4 * HH;         // 1 (+pad)
  float* pws = c0 + 4;              // 256 blocks * N * 4 unnormalized probs

  float* out_h = (float*)d_out;            // N*H
  float* out_x = out_h + NN * HH;          // N*2

  prep_kernel<<<dim3(HH), dim3(128), 0, stream>>>(
      Wq, Wk, Wv, We1, be1, We2, be2, Wc, bc, WqT, WkT, WvT, ep, c0);
  qkv_kernel<<<dim3(NN / QR), dim3(128), 0, stream>>>(
      h, WqT, WkT, WvT, bq, bk, bv, q_, kT, v_);
  fused_kernel<<<dim3(NN / RPB), dim3(TPB), 0, stream>>>(
      q_, kT, v_, h, x, ep, c0, pws, out_h, out_x);
}